// Round 13
// baseline (602.317 us; speedup 1.0000x reference)
//
#include <hip/hip_runtime.h>

#define FD 128      // feature dim (D == H == 128)
#define SCAN_B 256  // blocks in hierarchical scan
#define SCAN_T 256  // threads per scan block

typedef __attribute__((ext_vector_type(8))) short bf16x8;
typedef __attribute__((ext_vector_type(4))) float f32x4;

// ---------------- degree + per-edge rank (atomic return value is free) ----------------

__global__ void k_deg(const int* __restrict__ dst, int* __restrict__ deg,
                      int* __restrict__ rank, int E) {
  int e = blockIdx.x * blockDim.x + threadIdx.x;
  if (e < E) rank[e] = atomicAdd(&deg[dst[e]], 1);
}

// ---------------- hierarchical scan: partials (+ fused dinv) ----------------

__global__ __launch_bounds__(SCAN_T) void k_part(const int* __restrict__ deg,
                                                 float* __restrict__ dinv,
                                                 int* __restrict__ part, int n) {
  const int b = blockIdx.x;
  const int chunk = (n + SCAN_B - 1) / SCAN_B;
  const int lo = b * chunk;
  const int hi = min(lo + chunk, n);
  int sum = 0;
  for (int i = lo + threadIdx.x; i < hi; i += SCAN_T) {
    int d = deg[i];
    sum += d;
    dinv[i] = rsqrtf((float)(d + 1));   // +1 = self-loop
  }
  __shared__ int red[SCAN_T / 64];
  for (int off = 32; off > 0; off >>= 1) sum += __shfl_down(sum, off, 64);
  if ((threadIdx.x & 63) == 0) red[threadIdx.x >> 6] = sum;
  __syncthreads();
  if (threadIdx.x == 0) {
    int s = 0;
#pragma unroll
    for (int w = 0; w < SCAN_T / 64; ++w) s += red[w];
    part[b] = s;
  }
}

__global__ __launch_bounds__(SCAN_B) void k_scanpart(int* __restrict__ part,
                                                     int* __restrict__ row_ptr, int n) {
  __shared__ int s[SCAN_B];
  const int t = threadIdx.x;
  int v = part[t];
  s[t] = v;
  __syncthreads();
  for (int off = 1; off < SCAN_B; off <<= 1) {
    int u = (t >= off) ? s[t - off] : 0;
    __syncthreads();
    s[t] += u;
    __syncthreads();
  }
  part[t] = s[t] - v;                    // exclusive
  if (t == SCAN_B - 1) row_ptr[n] = s[t];
}

__global__ __launch_bounds__(SCAN_T) void k_rowptr(const int* __restrict__ deg,
                                                   const int* __restrict__ part,
                                                   int* __restrict__ row_ptr, int n) {
  const int b = blockIdx.x;
  const int chunk = (n + SCAN_B - 1) / SCAN_B;
  const int lo = b * chunk;
  const int hi = min(lo + chunk, n);
  const int sub = (chunk + SCAN_T - 1) / SCAN_T;
  const int t = threadIdx.x;
  const int slo = min(lo + t * sub, hi);
  const int shi = min(slo + sub, hi);
  int sum = 0;
  for (int i = slo; i < shi; ++i) sum += deg[i];
  __shared__ int s[SCAN_T];
  s[t] = sum;
  __syncthreads();
  for (int off = 1; off < SCAN_T; off <<= 1) {
    int u = (t >= off) ? s[t - off] : 0;
    __syncthreads();
    s[t] += u;
    __syncthreads();
  }
  int run = part[b] + s[t] - sum;
  for (int i = slo; i < shi; ++i) {
    row_ptr[i] = run;
    run += deg[i];
  }
}

// ---------------- CSR fill: atomic-free (pos = row_ptr[dst] + precomputed rank) ----------------

__global__ void k_fill(const int* __restrict__ src, const int* __restrict__ dst,
                       const int* __restrict__ rank, const int* __restrict__ row_ptr,
                       int* __restrict__ csr_src, int E) {
  int e = blockIdx.x * blockDim.x + threadIdx.x;
  if (e < E) {
    csr_src[row_ptr[dst[e]] + rank[e]] = src[e];
  }
}

// ---------------- split-bf16 MFMA GEMM: out = A @ W (+bias) ----------------
// A = hiA + loA, W = hiW + loW (bf16 RNE splits); out ≈ hiA·hiW + hiA·loW + loA·hiW
// (lo·lo dropped, ≤2^-18 relative). f32 MFMA accumulation. Tile 64 rows × 64 cols,
// K=128 fully staged in LDS. Fragment layout (m89-verified): A row=lane&15,
// B col=lane&15, k=(lane>>4)*8+i; D col=lane&15, row=(lane>>4)*4+reg.
// LDS rows padded 128->136 shorts: 272 B row stride = 16B-aligned (ds_read_b128 ok),
// 68 dwords -> +4 banks/row -> ~2-way conflicts (free, m136).

__device__ __forceinline__ void split_bf16(float x, short& hi, short& lo) {
  unsigned u = __float_as_uint(x);
  unsigned short h = (unsigned short)((u + 0x7fffu + ((u >> 16) & 1u)) >> 16);
  float hf = __uint_as_float((unsigned)h << 16);
  unsigned ul = __float_as_uint(x - hf);
  hi = (short)h;
  lo = (short)((ul + 0x7fffu + ((ul >> 16) & 1u)) >> 16);
}

__global__ __launch_bounds__(256) void k_gemm(const float* __restrict__ A, int lda,
                                              const float* __restrict__ W, int ldw,
                                              const float* __restrict__ bias,
                                              float* __restrict__ out, int ldo, int nrows) {
  __shared__ short xhi[64][136], xlo[64][136];   // [row][k]
  __shared__ short whi[64][136], wlo[64][136];   // transposed: [col][k]
  const int t  = threadIdx.x;
  const int r0 = blockIdx.x * 64;
  const int c0 = blockIdx.y * 64;

  // stage x: thread handles row t>>2, k-range [(t&3)*32, +32)
  {
    const int row  = t >> 2;
    const int kb   = (t & 3) * 32;
    const int grow = r0 + row;
    const float* ap = &A[(size_t)grow * lda + kb];
#pragma unroll
    for (int j = 0; j < 8; ++j) {
      float4 v = make_float4(0.f, 0.f, 0.f, 0.f);
      if (grow < nrows) v = *reinterpret_cast<const float4*>(ap + 4 * j);
      short4 h4, l4;
      split_bf16(v.x, h4.x, l4.x);
      split_bf16(v.y, h4.y, l4.y);
      split_bf16(v.z, h4.z, l4.z);
      split_bf16(v.w, h4.w, l4.w);
      *reinterpret_cast<short4*>(&xhi[row][kb + 4 * j]) = h4;
      *reinterpret_cast<short4*>(&xlo[row][kb + 4 * j]) = l4;
    }
  }
  // stage W transposed: thread handles k-row t>>1, col-range [(t&1)*32, +32)
  {
    const int k  = t >> 1;
    const int cb = (t & 1) * 32;
    const float* wp = &W[(size_t)k * ldw + c0 + cb];
#pragma unroll
    for (int j = 0; j < 8; ++j) {
      float4 v = *reinterpret_cast<const float4*>(wp + 4 * j);
      short h, l;
      split_bf16(v.x, h, l); whi[cb + 4 * j + 0][k] = h; wlo[cb + 4 * j + 0][k] = l;
      split_bf16(v.y, h, l); whi[cb + 4 * j + 1][k] = h; wlo[cb + 4 * j + 1][k] = l;
      split_bf16(v.z, h, l); whi[cb + 4 * j + 2][k] = h; wlo[cb + 4 * j + 2][k] = l;
      split_bf16(v.w, h, l); whi[cb + 4 * j + 3][k] = h; wlo[cb + 4 * j + 3][k] = l;
    }
  }
  __syncthreads();

  const int w  = t >> 6;   // wave id: rows [w*16, w*16+16)
  const int l  = t & 63;
  const int lr = l & 15;
  const int lk = l >> 4;   // 0..3

  f32x4 acc[4] = {};       // 4 col-tiles of 16
#pragma unroll
  for (int kc = 0; kc < 4; ++kc) {
    const int kb = kc * 32 + lk * 8;
    const bf16x8 ah = *reinterpret_cast<const bf16x8*>(&xhi[w * 16 + lr][kb]);
    const bf16x8 al = *reinterpret_cast<const bf16x8*>(&xlo[w * 16 + lr][kb]);
#pragma unroll
    for (int ct = 0; ct < 4; ++ct) {
      const bf16x8 bh = *reinterpret_cast<const bf16x8*>(&whi[ct * 16 + lr][kb]);
      const bf16x8 bl = *reinterpret_cast<const bf16x8*>(&wlo[ct * 16 + lr][kb]);
      acc[ct] = __builtin_amdgcn_mfma_f32_16x16x32_bf16(ah, bh, acc[ct], 0, 0, 0);
      acc[ct] = __builtin_amdgcn_mfma_f32_16x16x32_bf16(ah, bl, acc[ct], 0, 0, 0);
      acc[ct] = __builtin_amdgcn_mfma_f32_16x16x32_bf16(al, bh, acc[ct], 0, 0, 0);
    }
  }

#pragma unroll
  for (int ct = 0; ct < 4; ++ct) {
    const int col = c0 + ct * 16 + lr;
    const float b = bias ? bias[col] : 0.f;
#pragma unroll
    for (int r = 0; r < 4; ++r) {
      const int row = r0 + w * 16 + lk * 4 + r;
      if (row < nrows) out[(size_t)row * ldo + col] = acc[ct][r] + b;
    }
  }
}

// ---------------- aggregation: out[n] = relu( sum_in h[s]*dinv[s]*di + h[n]*di*di + b ) ----
// one 64-lane wave per node; lane holds float4 (32 lanes span the 128-dim row);
// the two wave-halves process two edges per gather instruction (1 KB/instr);
// final __shfl_xor(32) merges halves. coef recomputed from L2-resident dinv.

__global__ __launch_bounds__(256) void k_agg(const float* __restrict__ h,
                                             const int* __restrict__ row_ptr,
                                             const int* __restrict__ csr_src,
                                             const float* __restrict__ dinv,
                                             const float* __restrict__ bias,
                                             float* __restrict__ out, int n) {
  const int node = blockIdx.x * 4 + (threadIdx.x >> 6);
  if (node >= n) return;
  const int lane = threadIdx.x & 63;
  const int sub  = lane >> 5;          // which edge of the pair this half-wave takes
  const int c4   = (lane & 31) << 2;   // feature quad base
  const float di = dinv[node];

  float4 acc = make_float4(0.f, 0.f, 0.f, 0.f);
  const int e0 = row_ptr[node], e1 = row_ptr[node + 1];
  int e = e0;
  for (; e + 8 <= e1; e += 8) {
    const int ia = csr_src[e     + sub];
    const int ib = csr_src[e + 2 + sub];
    const int ic = csr_src[e + 4 + sub];
    const int id = csr_src[e + 6 + sub];
    const float4 va = *reinterpret_cast<const float4*>(&h[(size_t)ia * FD + c4]);
    const float4 vb = *reinterpret_cast<const float4*>(&h[(size_t)ib * FD + c4]);
    const float4 vc = *reinterpret_cast<const float4*>(&h[(size_t)ic * FD + c4]);
    const float4 vd = *reinterpret_cast<const float4*>(&h[(size_t)id * FD + c4]);
    const float ca = dinv[ia] * di;
    const float cb = dinv[ib] * di;
    const float cc = dinv[ic] * di;
    const float cd = dinv[id] * di;
    acc.x += va.x * ca + vb.x * cb + vc.x * cc + vd.x * cd;
    acc.y += va.y * ca + vb.y * cb + vc.y * cc + vd.y * cd;
    acc.z += va.z * ca + vb.z * cb + vc.z * cc + vd.z * cd;
    acc.w += va.w * ca + vb.w * cb + vc.w * cc + vd.w * cd;
  }
  for (; e + 2 <= e1; e += 2) {
    const int i0 = csr_src[e + sub];
    const float4 v = *reinterpret_cast<const float4*>(&h[(size_t)i0 * FD + c4]);
    const float c = dinv[i0] * di;
    acc.x += v.x * c; acc.y += v.y * c; acc.z += v.z * c; acc.w += v.w * c;
  }
  if (e < e1 && sub == 0) {            // odd tail: first half-wave only
    const int i0 = csr_src[e];
    const float4 v = *reinterpret_cast<const float4*>(&h[(size_t)i0 * FD + c4]);
    const float c = dinv[i0] * di;
    acc.x += v.x * c; acc.y += v.y * c; acc.z += v.z * c; acc.w += v.w * c;
  }

  // merge the two half-waves (lane ^ 32 holds the other edge-subset's partial)
  acc.x += __shfl_xor(acc.x, 32);
  acc.y += __shfl_xor(acc.y, 32);
  acc.z += __shfl_xor(acc.z, 32);
  acc.w += __shfl_xor(acc.w, 32);

  const float4 hs = *reinterpret_cast<const float4*>(&h[(size_t)node * FD + c4]);
  const float4 b4 = *reinterpret_cast<const float4*>(&bias[c4]);
  float4 o;
  o.x = fmaxf(acc.x + hs.x * di * di + b4.x, 0.f);
  o.y = fmaxf(acc.y + hs.y * di * di + b4.y, 0.f);
  o.z = fmaxf(acc.z + hs.z * di * di + b4.z, 0.f);
  o.w = fmaxf(acc.w + hs.w * di * di + b4.w, 0.f);
  if (sub == 0)
    *reinterpret_cast<float4*>(&out[(size_t)node * FD + c4]) = o;
}

// ---------------- launch ----------------

extern "C" void kernel_launch(void* const* d_in, const int* in_sizes, int n_in,
                              void* d_out, int out_size, void* d_ws, size_t ws_size,
                              hipStream_t stream) {
  const float* x  = (const float*)d_in[0];
  const float* W1 = (const float*)d_in[1];
  const float* b1 = (const float*)d_in[2];
  const float* W2 = (const float*)d_in[3];
  const float* b2 = (const float*)d_in[4];
  const float* Wf = (const float*)d_in[5];
  const float* bf = (const float*)d_in[6];
  const int*   ei = (const int*)d_in[7];

  const int N = in_sizes[0] / FD;
  const int E = in_sizes[7] / 2;
  const int O = in_sizes[6];
  const int* src = ei;
  const int* dst = ei + E;

  char* ws = (char*)d_ws;
  size_t off = 0;
  auto alloc = [&](size_t bytes) -> void* {
    void* p = ws + off;
    off += (bytes + 255) & ~(size_t)255;
    return p;
  };
  float* A       = (float*)alloc((size_t)N * FD * 4);
  float* B       = (float*)alloc((size_t)N * FD * 4);
  int*   deg     = (int*)  alloc((size_t)N * 4);
  float* dinv    = (float*)alloc((size_t)N * 4);
  int*   row_ptr = (int*)  alloc((size_t)(N + 1) * 4);
  int*   rank    = (int*)  alloc((size_t)E * 4);
  int*   csr_src = (int*)  alloc((size_t)E * 4);
  int*   part    = (int*)  alloc((size_t)SCAN_B * 4);

  hipMemsetAsync(deg, 0, (size_t)N * 4, stream);
  k_deg     <<<(E + 255) / 256, 256, 0, stream>>>(dst, deg, rank, E);
  k_part    <<<SCAN_B, SCAN_T, 0, stream>>>(deg, dinv, part, N);
  k_scanpart<<<1, SCAN_B, 0, stream>>>(part, row_ptr, N);
  k_rowptr  <<<SCAN_B, SCAN_T, 0, stream>>>(deg, part, row_ptr, N);
  k_fill    <<<(E + 255) / 256, 256, 0, stream>>>(src, dst, rank, row_ptr, csr_src, E);

  const int gx = (N + 63) / 64;
  // layer 1: h = x@W1 ; agg+b1+relu
  k_gemm<<<dim3(gx, 2), 256, 0, stream>>>(x, FD, W1, FD, nullptr, A, FD, N);
  k_agg <<<(N + 3) / 4, 256, 0, stream>>>(A, row_ptr, csr_src, dinv, b1, B, N);
  // layer 2
  k_gemm<<<dim3(gx, 2), 256, 0, stream>>>(B, FD, W2, FD, nullptr, A, FD, N);
  k_agg <<<(N + 3) / 4, 256, 0, stream>>>(A, row_ptr, csr_src, dinv, b2, B, N);
  // final linear (O = 64 cols -> single column-block)
  k_gemm<<<dim3(gx, 1), 256, 0, stream>>>(B, FD, Wf, O, bf, (float*)d_out, O, N);
}

// Round 14
// 573.201 us; speedup vs baseline: 1.0508x; 1.0508x over previous
//
#include <hip/hip_runtime.h>

#define FD 128      // feature dim (D == H == 128)
#define SCAN_B 256  // blocks in hierarchical scan
#define SCAN_T 256  // threads per scan block

typedef __attribute__((ext_vector_type(8))) short bf16x8;
typedef __attribute__((ext_vector_type(4))) float f32x4;

// ---------------- degree + per-edge rank (atomic return value is free) ----------------

__global__ void k_deg(const int* __restrict__ dst, int* __restrict__ deg,
                      int* __restrict__ rank, int E) {
  int e = blockIdx.x * blockDim.x + threadIdx.x;
  if (e < E) rank[e] = atomicAdd(&deg[dst[e]], 1);
}

// ---------------- per-chunk partial sums (+ fused dinv) ----------------

__global__ __launch_bounds__(SCAN_T) void k_part(const int* __restrict__ deg,
                                                 float* __restrict__ dinv,
                                                 int* __restrict__ part, int n) {
  const int b = blockIdx.x;
  const int chunk = (n + SCAN_B - 1) / SCAN_B;
  const int lo = b * chunk;
  const int hi = min(lo + chunk, n);
  int sum = 0;
  for (int i = lo + threadIdx.x; i < hi; i += SCAN_T) {
    int d = deg[i];
    sum += d;
    dinv[i] = rsqrtf((float)(d + 1));   // +1 = self-loop
  }
  __shared__ int red[SCAN_T / 64];
  for (int off = 32; off > 0; off >>= 1) sum += __shfl_down(sum, off, 64);
  if ((threadIdx.x & 63) == 0) red[threadIdx.x >> 6] = sum;
  __syncthreads();
  if (threadIdx.x == 0) {
    int s = 0;
#pragma unroll
    for (int w = 0; w < SCAN_T / 64; ++w) s += red[w];
    part[b] = s;
  }
}

// ---------------- row_ptr: inline scan of raw partials (k_scanpart eliminated) ----------------

__global__ __launch_bounds__(SCAN_T) void k_rowptr(const int* __restrict__ deg,
                                                   const int* __restrict__ part,
                                                   int* __restrict__ row_ptr, int n) {
  __shared__ int ps[SCAN_B];   // inclusive scan of the 256 raw partials (redundant per block)
  __shared__ int s[SCAN_T];
  const int t = threadIdx.x;
  const int b = blockIdx.x;
  ps[t] = part[t];
  __syncthreads();
  for (int off = 1; off < SCAN_B; off <<= 1) {
    int u = (t >= off) ? ps[t - off] : 0;
    __syncthreads();
    ps[t] += u;
    __syncthreads();
  }
  const int excl = (b == 0) ? 0 : ps[b - 1];  // exclusive global base for this chunk
  if (b == 0 && t == 0) row_ptr[n] = ps[SCAN_B - 1];

  const int chunk = (n + SCAN_B - 1) / SCAN_B;
  const int lo = b * chunk;
  const int hi = min(lo + chunk, n);
  const int sub = (chunk + SCAN_T - 1) / SCAN_T;
  const int slo = min(lo + t * sub, hi);
  const int shi = min(slo + sub, hi);
  int sum = 0;
  for (int i = slo; i < shi; ++i) sum += deg[i];
  s[t] = sum;
  __syncthreads();
  for (int off = 1; off < SCAN_T; off <<= 1) {
    int u = (t >= off) ? s[t - off] : 0;
    __syncthreads();
    s[t] += u;
    __syncthreads();
  }
  int run = excl + s[t] - sum;
  for (int i = slo; i < shi; ++i) {
    row_ptr[i] = run;
    run += deg[i];
  }
}

// ---------------- split-bf16 helpers ----------------

__device__ __forceinline__ void split_bf16(float x, short& hi, short& lo) {
  unsigned u = __float_as_uint(x);
  unsigned short h = (unsigned short)((u + 0x7fffu + ((u >> 16) & 1u)) >> 16);
  float hf = __uint_as_float((unsigned)h << 16);
  unsigned ul = __float_as_uint(x - hf);
  hi = (short)h;
  lo = (short)((ul + 0x7fffu + ((ul >> 16) & 1u)) >> 16);
}

// ---------------- GEMM body (shared by fused and standalone kernels) ----------------
// out = A @ W (+bias); A = hiA+loA, W = hiW+loW (bf16 RNE); hi·hi + hi·lo + lo·hi.
// 64×64 tile, K=128 in LDS; m89-verified fragment layout.

__device__ __forceinline__ void gemm_body(
    short (*xhi)[136], short (*xlo)[136], short (*whi)[136], short (*wlo)[136],
    int t, int r0, int c0,
    const float* __restrict__ A, int lda, const float* __restrict__ W, int ldw,
    const float* __restrict__ bias, float* __restrict__ out, int ldo, int nrows) {
  // stage x: thread handles row t>>2, k-range [(t&3)*32, +32)
  {
    const int row  = t >> 2;
    const int kb   = (t & 3) * 32;
    const int grow = r0 + row;
    const float* ap = &A[(size_t)grow * lda + kb];
#pragma unroll
    for (int j = 0; j < 8; ++j) {
      float4 v = make_float4(0.f, 0.f, 0.f, 0.f);
      if (grow < nrows) v = *reinterpret_cast<const float4*>(ap + 4 * j);
      short4 h4, l4;
      split_bf16(v.x, h4.x, l4.x);
      split_bf16(v.y, h4.y, l4.y);
      split_bf16(v.z, h4.z, l4.z);
      split_bf16(v.w, h4.w, l4.w);
      *reinterpret_cast<short4*>(&xhi[row][kb + 4 * j]) = h4;
      *reinterpret_cast<short4*>(&xlo[row][kb + 4 * j]) = l4;
    }
  }
  // stage W transposed: thread handles k-row t>>1, col-range [(t&1)*32, +32)
  {
    const int k  = t >> 1;
    const int cb = (t & 1) * 32;
    const float* wp = &W[(size_t)k * ldw + c0 + cb];
#pragma unroll
    for (int j = 0; j < 8; ++j) {
      float4 v = *reinterpret_cast<const float4*>(wp + 4 * j);
      short h, l;
      split_bf16(v.x, h, l); whi[cb + 4 * j + 0][k] = h; wlo[cb + 4 * j + 0][k] = l;
      split_bf16(v.y, h, l); whi[cb + 4 * j + 1][k] = h; wlo[cb + 4 * j + 1][k] = l;
      split_bf16(v.z, h, l); whi[cb + 4 * j + 2][k] = h; wlo[cb + 4 * j + 2][k] = l;
      split_bf16(v.w, h, l); whi[cb + 4 * j + 3][k] = h; wlo[cb + 4 * j + 3][k] = l;
    }
  }
  __syncthreads();

  const int w  = t >> 6;   // wave id: rows [w*16, w*16+16)
  const int l  = t & 63;
  const int lr = l & 15;
  const int lk = l >> 4;   // 0..3

  f32x4 acc[4] = {};       // 4 col-tiles of 16
#pragma unroll
  for (int kc = 0; kc < 4; ++kc) {
    const int kb = kc * 32 + lk * 8;
    const bf16x8 ah = *reinterpret_cast<const bf16x8*>(&xhi[w * 16 + lr][kb]);
    const bf16x8 al = *reinterpret_cast<const bf16x8*>(&xlo[w * 16 + lr][kb]);
#pragma unroll
    for (int ct = 0; ct < 4; ++ct) {
      const bf16x8 bh = *reinterpret_cast<const bf16x8*>(&whi[ct * 16 + lr][kb]);
      const bf16x8 bl = *reinterpret_cast<const bf16x8*>(&wlo[ct * 16 + lr][kb]);
      acc[ct] = __builtin_amdgcn_mfma_f32_16x16x32_bf16(ah, bh, acc[ct], 0, 0, 0);
      acc[ct] = __builtin_amdgcn_mfma_f32_16x16x32_bf16(ah, bl, acc[ct], 0, 0, 0);
      acc[ct] = __builtin_amdgcn_mfma_f32_16x16x32_bf16(al, bh, acc[ct], 0, 0, 0);
    }
  }

#pragma unroll
  for (int ct = 0; ct < 4; ++ct) {
    const int col = c0 + ct * 16 + lr;
    const float b = bias ? bias[col] : 0.f;
#pragma unroll
    for (int r = 0; r < 4; ++r) {
      const int row = r0 + w * 16 + lk * 4 + r;
      if (row < nrows) out[(size_t)row * ldo + col] = acc[ct][r] + b;
    }
  }
}

// ---------------- fused CSR-fill + GEMM1 (independent workloads join at agg1) ----------------
// blocks [0, nfb): scatter fill (latency-bound, ~0% VALU); blocks [nfb, nfb+2*gx): GEMM1
// (MFMA/LDS-bound). Co-residency overlaps the two chains' tails.

__global__ __launch_bounds__(256) void k_fill_gemm(
    const int* __restrict__ src, const int* __restrict__ dst,
    const int* __restrict__ rank, const int* __restrict__ row_ptr,
    int* __restrict__ csr_src, int E, int nfb,
    const float* __restrict__ A, int lda, const float* __restrict__ W, int ldw,
    float* __restrict__ out, int ldo, int nrows, int gx) {
  __shared__ short xhi[64][136], xlo[64][136];
  __shared__ short whi[64][136], wlo[64][136];
  const int t = threadIdx.x;
  if ((int)blockIdx.x < nfb) {
    const int e = blockIdx.x * 256 + t;
    if (e < E) csr_src[row_ptr[dst[e]] + rank[e]] = src[e];
    return;
  }
  const int gid = (int)blockIdx.x - nfb;
  gemm_body(xhi, xlo, whi, wlo, t, (gid % gx) * 64, (gid / gx) * 64,
            A, lda, W, ldw, nullptr, out, ldo, nrows);
}

// ---------------- standalone GEMM (layers 2 and 3) ----------------

__global__ __launch_bounds__(256) void k_gemm(const float* __restrict__ A, int lda,
                                              const float* __restrict__ W, int ldw,
                                              const float* __restrict__ bias,
                                              float* __restrict__ out, int ldo, int nrows) {
  __shared__ short xhi[64][136], xlo[64][136];
  __shared__ short whi[64][136], wlo[64][136];
  gemm_body(xhi, xlo, whi, wlo, threadIdx.x, blockIdx.x * 64, blockIdx.y * 64,
            A, lda, W, ldw, bias, out, ldo, nrows);
}

// ---------------- aggregation: out[n] = relu( sum_in h[s]*dinv[s]*di + h[n]*di*di + b ) ----
// one 64-lane wave per node; lane holds float4 (32 lanes span the 128-dim row);
// the two wave-halves process two edges per gather instruction (1 KB/instr);
// final __shfl_xor(32) merges halves. coef recomputed from L2-resident dinv.

__global__ __launch_bounds__(256) void k_agg(const float* __restrict__ h,
                                             const int* __restrict__ row_ptr,
                                             const int* __restrict__ csr_src,
                                             const float* __restrict__ dinv,
                                             const float* __restrict__ bias,
                                             float* __restrict__ out, int n) {
  const int node = blockIdx.x * 4 + (threadIdx.x >> 6);
  if (node >= n) return;
  const int lane = threadIdx.x & 63;
  const int sub  = lane >> 5;          // which edge of the pair this half-wave takes
  const int c4   = (lane & 31) << 2;   // feature quad base
  const float di = dinv[node];

  float4 acc = make_float4(0.f, 0.f, 0.f, 0.f);
  const int e0 = row_ptr[node], e1 = row_ptr[node + 1];
  int e = e0;
  for (; e + 8 <= e1; e += 8) {
    const int ia = csr_src[e     + sub];
    const int ib = csr_src[e + 2 + sub];
    const int ic = csr_src[e + 4 + sub];
    const int id = csr_src[e + 6 + sub];
    const float4 va = *reinterpret_cast<const float4*>(&h[(size_t)ia * FD + c4]);
    const float4 vb = *reinterpret_cast<const float4*>(&h[(size_t)ib * FD + c4]);
    const float4 vc = *reinterpret_cast<const float4*>(&h[(size_t)ic * FD + c4]);
    const float4 vd = *reinterpret_cast<const float4*>(&h[(size_t)id * FD + c4]);
    const float ca = dinv[ia] * di;
    const float cb = dinv[ib] * di;
    const float cc = dinv[ic] * di;
    const float cd = dinv[id] * di;
    acc.x += va.x * ca + vb.x * cb + vc.x * cc + vd.x * cd;
    acc.y += va.y * ca + vb.y * cb + vc.y * cc + vd.y * cd;
    acc.z += va.z * ca + vb.z * cb + vc.z * cc + vd.z * cd;
    acc.w += va.w * ca + vb.w * cb + vc.w * cc + vd.w * cd;
  }
  for (; e + 2 <= e1; e += 2) {
    const int i0 = csr_src[e + sub];
    const float4 v = *reinterpret_cast<const float4*>(&h[(size_t)i0 * FD + c4]);
    const float c = dinv[i0] * di;
    acc.x += v.x * c; acc.y += v.y * c; acc.z += v.z * c; acc.w += v.w * c;
  }
  if (e < e1 && sub == 0) {            // odd tail: first half-wave only
    const int i0 = csr_src[e];
    const float4 v = *reinterpret_cast<const float4*>(&h[(size_t)i0 * FD + c4]);
    const float c = dinv[i0] * di;
    acc.x += v.x * c; acc.y += v.y * c; acc.z += v.z * c; acc.w += v.w * c;
  }

  // merge the two half-waves (lane ^ 32 holds the other edge-subset's partial)
  acc.x += __shfl_xor(acc.x, 32);
  acc.y += __shfl_xor(acc.y, 32);
  acc.z += __shfl_xor(acc.z, 32);
  acc.w += __shfl_xor(acc.w, 32);

  const float4 hs = *reinterpret_cast<const float4*>(&h[(size_t)node * FD + c4]);
  const float4 b4 = *reinterpret_cast<const float4*>(&bias[c4]);
  float4 o;
  o.x = fmaxf(acc.x + hs.x * di * di + b4.x, 0.f);
  o.y = fmaxf(acc.y + hs.y * di * di + b4.y, 0.f);
  o.z = fmaxf(acc.z + hs.z * di * di + b4.z, 0.f);
  o.w = fmaxf(acc.w + hs.w * di * di + b4.w, 0.f);
  if (sub == 0)
    *reinterpret_cast<float4*>(&out[(size_t)node * FD + c4]) = o;
}

// ---------------- launch ----------------

extern "C" void kernel_launch(void* const* d_in, const int* in_sizes, int n_in,
                              void* d_out, int out_size, void* d_ws, size_t ws_size,
                              hipStream_t stream) {
  const float* x  = (const float*)d_in[0];
  const float* W1 = (const float*)d_in[1];
  const float* b1 = (const float*)d_in[2];
  const float* W2 = (const float*)d_in[3];
  const float* b2 = (const float*)d_in[4];
  const float* Wf = (const float*)d_in[5];
  const float* bf = (const float*)d_in[6];
  const int*   ei = (const int*)d_in[7];

  const int N = in_sizes[0] / FD;
  const int E = in_sizes[7] / 2;
  const int O = in_sizes[6];
  const int* src = ei;
  const int* dst = ei + E;

  char* ws = (char*)d_ws;
  size_t off = 0;
  auto alloc = [&](size_t bytes) -> void* {
    void* p = ws + off;
    off += (bytes + 255) & ~(size_t)255;
    return p;
  };
  float* A       = (float*)alloc((size_t)N * FD * 4);
  float* B       = (float*)alloc((size_t)N * FD * 4);
  int*   deg     = (int*)  alloc((size_t)N * 4);
  float* dinv    = (float*)alloc((size_t)N * 4);
  int*   row_ptr = (int*)  alloc((size_t)(N + 1) * 4);
  int*   rank    = (int*)  alloc((size_t)E * 4);
  int*   csr_src = (int*)  alloc((size_t)E * 4);
  int*   part    = (int*)  alloc((size_t)SCAN_B * 4);

  const int gx  = (N + 63) / 64;
  const int nfb = (E + 255) / 256;

  hipMemsetAsync(deg, 0, (size_t)N * 4, stream);
  k_deg   <<<(E + 255) / 256, 256, 0, stream>>>(dst, deg, rank, E);
  k_part  <<<SCAN_B, SCAN_T, 0, stream>>>(deg, dinv, part, N);
  k_rowptr<<<SCAN_B, SCAN_T, 0, stream>>>(deg, part, row_ptr, N);

  // fused: CSR fill (blocks [0,nfb)) + layer-1 GEMM h=x@W1 (blocks [nfb, nfb+2*gx))
  k_fill_gemm<<<nfb + 2 * gx, 256, 0, stream>>>(src, dst, rank, row_ptr, csr_src, E, nfb,
                                                x, FD, W1, FD, A, FD, N, gx);
  k_agg <<<(N + 3) / 4, 256, 0, stream>>>(A, row_ptr, csr_src, dinv, b1, B, N);
  // layer 2
  k_gemm<<<dim3(gx, 2), 256, 0, stream>>>(B, FD, W2, FD, nullptr, A, FD, N);
  k_agg <<<(N + 3) / 4, 256, 0, stream>>>(A, row_ptr, csr_src, dinv, b2, B, N);
  // final linear (O = 64 cols -> single column-block)
  k_gemm<<<dim3(gx, 1), 256, 0, stream>>>(B, FD, Wf, O, bf, (float*)d_out, O, N);
}